// Round 7
// baseline (523.041 us; speedup 1.0000x reference)
//
#include <hip/hip_runtime.h>
#include <math.h>

#define DD    128
#define NQQ   7
#define NB    1024
#define TRI   8256
#define NSQ   2          // squarings (scale 1/4); theta<=1.45, Y-norm<=2.1
#define CSTR  136        // bf16 elems per chunk row (272 B = 17 x 16B granules)
#define FSTR  132        // fp32 elems per row in fp32 overlay

typedef short  bf16x8 __attribute__((ext_vector_type(8)));
typedef short  s16x4  __attribute__((ext_vector_type(4)));
typedef float  f32x16 __attribute__((ext_vector_type(16)));

// truncation hi/lo split: hi = top16(v), lo = top16(v - hi)  (~4 VALU ops)
__device__ __forceinline__ void split2(float v, unsigned short& h, unsigned short& l) {
  unsigned u = __builtin_bit_cast(unsigned, v);
  float hf = __builtin_bit_cast(float, u & 0xFFFF0000u);
  float lf = v - hf;
  h = (unsigned short)(u >> 16);
  l = (unsigned short)(__builtin_bit_cast(unsigned, lf) >> 16);
}
__device__ __forceinline__ float bf2f(unsigned short s) {
  return __builtin_bit_cast(float, ((unsigned)s) << 16);
}
__device__ __forceinline__ f32x16 MF(bf16x8 a, bf16x8 b, f32x16 c) {
  return __builtin_amdgcn_mfma_f32_32x32x16_bf16(a, b, c, 0, 0, 0);
}
__device__ __forceinline__ bf16x8 NEG(bf16x8 a) {
  int4 u = __builtin_bit_cast(int4, a);
  u.x ^= 0x80008000; u.y ^= 0x80008000; u.z ^= 0x80008000; u.w ^= 0x80008000;
  return __builtin_bit_cast(bf16x8, u);
}
__device__ __forceinline__ bf16x8 LDF(const unsigned short* C, int row, int s, int hb) {
  return *reinterpret_cast<const bf16x8*>(C + row * CSTR + s * 16 + hb * 8);
}

// amdgpu_waves_per_eu(2,2): 8-wave block, 1 block/CU (LDS-capped) = 2 waves/EU;
// lifts VGPR budget to 256. launch_bounds(512,2) alone was IGNORED (R6: VGPR
// stayed 128, 313MB/dispatch scratch). Phase 4 additionally restructured to
// 2 accumulators/pass so it fits 128 even if the attribute is also ignored.
__global__ __launch_bounds__(512) __attribute__((amdgpu_waves_per_eu(2, 2)))
void loss_k(
    const float* __restrict__ flat,
    const float* __restrict__ timev,
    const float* __restrict__ state,
    const int*   __restrict__ tgt,
    const int*   __restrict__ basis,
    float* __restrict__ ws)
{
  __shared__ __align__(16) char lds[4 * 128 * CSTR * 2 + 8192];
  unsigned short* C0 = (unsigned short*)lds;
  unsigned short* C1 = C0 + 128 * CSTR;
  unsigned short* C2 = C1 + 128 * CSTR;
  unsigned short* C3 = C2 + 128 * CSTR;
  float* AUX = (float*)(lds + 4 * 128 * CSTR * 2);   // 2048 floats
  float* Urf = (float*)lds;                          // fp32 overlay (aliases chunks)
  float* Uif = Urf + 128 * FSTR;

  const int b    = blockIdx.x;
  const int tid  = threadIdx.x;
  const int wid  = tid >> 6;
  const int lane = tid & 63;
  const int l31  = lane & 31;
  const int hb   = lane >> 5;

  const int tr    = wid >> 1;
  const int tcb   = (wid & 1) * 2;
  const int arow  = 32 * tr + l31;
  const int bcol0 = 32 * tcb + l31;
  const int bcol1 = 32 * (tcb + 1) + l31;

  const float tval  = timev[b];
  const float alpha = 0.25f * tval * 0.25f;     // DS * t / 2^NSQ
  const float* fb = flat + (size_t)b * TRI;

  // store a product-register tile (scaled) as hi/lo chunks at column BCOL
#define STORE_TILE(PREG, SCALE, BCOL, DH, DL) do {                         \
    _Pragma("unroll")                                                      \
    for (int q_ = 0; q_ < 4; ++q_) {                                       \
      s16x4 hh_, ll_;                                                      \
      _Pragma("unroll")                                                    \
      for (int rr_ = 0; rr_ < 4; ++rr_) {                                  \
        unsigned short h_, l_;                                             \
        split2((SCALE) * (PREG)[4 * q_ + rr_], h_, l_);                    \
        hh_[rr_] = (short)h_; ll_[rr_] = (short)l_;                        \
      }                                                                    \
      int off_ = (BCOL) * CSTR + 32 * tr + 8 * q_ + 4 * hb;                \
      *(s16x4*)((DH) + off_) = hh_; *(s16x4*)((DL) + off_) = ll_;          \
    }                                                                      \
  } while (0)

  // ---- Phase 0: stage X = alpha*M into C0/C1 (hi/lo) ----
  for (int e = tid; e < DD * DD; e += 512) {
    int i = e >> 7, j = e & 127;
    int r = i >= j ? i : j, c = i >= j ? j : i;
    float v = alpha * fb[(r * (r + 1)) / 2 + c];
    unsigned short h, l; split2(v, h, l);
    C0[i * CSTR + j] = h;  C1[i * CSTR + j] = l;
  }
  __syncthreads();

  f32x16 p0, p1, Cc0, Cc1, Qc0, Qc1;

  // ---- Y = X @ X ----
#pragma unroll
  for (int e = 0; e < 16; ++e) { p0[e] = 0.0f; p1[e] = 0.0f; }
#pragma unroll
  for (int s = 0; s < 8; ++s) {
    bf16x8 ah = LDF(C0, arow, s, hb),  al = LDF(C1, arow, s, hb);
    bf16x8 b0h = LDF(C0, bcol0, s, hb), b0l = LDF(C1, bcol0, s, hb);
    bf16x8 b1h = LDF(C0, bcol1, s, hb), b1l = LDF(C1, bcol1, s, hb);
    p0 = MF(ah, b0h, p0); p0 = MF(ah, b0l, p0); p0 = MF(al, b0h, p0);
    p1 = MF(ah, b1h, p1); p1 = MF(ah, b1l, p1); p1 = MF(al, b1h, p1);
  }
  __syncthreads();
  // init C = I - Y/2 + ..., Q = I - Y/6 + ...
#pragma unroll
  for (int q = 0; q < 4; ++q) {
#pragma unroll
    for (int rr = 0; rr < 4; ++rr) {
      int e = 4 * q + rr;
      int rg = 32 * tr + 8 * q + 4 * hb + rr;
      float i0 = (rg == bcol0) ? 1.0f : 0.0f;
      float i1 = (rg == bcol1) ? 1.0f : 0.0f;
      Cc0[e] = i0 - 0.5f * p0[e];            Cc1[e] = i1 - 0.5f * p1[e];
      Qc0[e] = i0 - 0.16666667f * p0[e];     Qc1[e] = i1 - 0.16666667f * p1[e];
    }
  }
  STORE_TILE(p0, 1.0f, bcol0, C2, C3);       // Y -> C2/C3
  STORE_TILE(p1, 1.0f, bcol1, C2, C3);
  __syncthreads();

  // ---- j=2: Z2 = Y @ Y -> C0/C1 (X dead, rebuilt later) ----
#pragma unroll
  for (int e = 0; e < 16; ++e) { p0[e] = 0.0f; p1[e] = 0.0f; }
#pragma unroll
  for (int s = 0; s < 8; ++s) {
    bf16x8 ah = LDF(C2, arow, s, hb),  al = LDF(C3, arow, s, hb);
    bf16x8 b0h = LDF(C2, bcol0, s, hb), b0l = LDF(C3, bcol0, s, hb);
    bf16x8 b1h = LDF(C2, bcol1, s, hb), b1l = LDF(C3, bcol1, s, hb);
    p0 = MF(ah, b0h, p0); p0 = MF(ah, b0l, p0); p0 = MF(al, b0h, p0);
    p1 = MF(ah, b1h, p1); p1 = MF(ah, b1l, p1); p1 = MF(al, b1h, p1);
  }
  __syncthreads();
#pragma unroll
  for (int e = 0; e < 16; ++e) {
    Cc0[e] += 4.1666668e-2f * p0[e];  Cc1[e] += 4.1666668e-2f * p1[e];
    Qc0[e] += 8.3333333e-3f * p0[e];  Qc1[e] += 8.3333333e-3f * p1[e];
  }
  STORE_TILE(p0, 1.0f, bcol0, C0, C1);
  STORE_TILE(p1, 1.0f, bcol1, C0, C1);
  __syncthreads();

  // ---- j=3..8: Z_j = Y @ Z_{j-1}; C += c_j Z_j; Q += q_j Z_j (j<8) ----
  const float CJ[9] = {0.f, 0.f, 0.f, -1.3888889e-3f, 2.4801587e-5f,
                       -2.7557319e-7f, 2.0876757e-9f, -1.1470746e-11f, 4.7794773e-14f};
  const float QJ[8] = {0.f, 0.f, 0.f, -1.9841270e-4f, 2.7557319e-6f,
                       -2.5052108e-8f, 1.6059044e-10f, -7.6471637e-13f};
#pragma unroll
  for (int j = 3; j <= 8; ++j) {
#pragma unroll
    for (int e = 0; e < 16; ++e) { p0[e] = 0.0f; p1[e] = 0.0f; }
#pragma unroll
    for (int s = 0; s < 8; ++s) {
      bf16x8 ah = LDF(C2, arow, s, hb),  al = LDF(C3, arow, s, hb);
      bf16x8 b0h = LDF(C0, bcol0, s, hb), b0l = LDF(C1, bcol0, s, hb);
      bf16x8 b1h = LDF(C0, bcol1, s, hb), b1l = LDF(C1, bcol1, s, hb);
      p0 = MF(ah, b0h, p0); p0 = MF(ah, b0l, p0); p0 = MF(al, b0h, p0);
      p1 = MF(ah, b1h, p1); p1 = MF(ah, b1l, p1); p1 = MF(al, b1h, p1);
    }
    __syncthreads();
#pragma unroll
    for (int e = 0; e < 16; ++e) { Cc0[e] += CJ[j] * p0[e]; Cc1[e] += CJ[j] * p1[e]; }
    if (j < 8) {
#pragma unroll
      for (int e = 0; e < 16; ++e) { Qc0[e] += QJ[j] * p0[e]; Qc1[e] += QJ[j] * p1[e]; }
      STORE_TILE(p0, 1.0f, bcol0, C0, C1);
      STORE_TILE(p1, 1.0f, bcol1, C0, C1);
    }
    __syncthreads();
  }

  // ---- Write Q -> C2/C3 (over Y); rebuild X -> C0/C1 (over Z7) ----
  STORE_TILE(Qc0, 1.0f, bcol0, C2, C3);
  STORE_TILE(Qc1, 1.0f, bcol1, C2, C3);
  for (int e = tid; e < DD * DD; e += 512) {
    int i = e >> 7, j = e & 127;
    int r = i >= j ? i : j, c = i >= j ? j : i;
    float v = alpha * fb[(r * (r + 1)) / 2 + c];
    unsigned short h, l; split2(v, h, l);
    C0[i * CSTR + j] = h;  C1[i * CSTR + j] = l;
  }
  __syncthreads();

  // ---- S = X @ Q  (sin) ----
#pragma unroll
  for (int e = 0; e < 16; ++e) { p0[e] = 0.0f; p1[e] = 0.0f; }
#pragma unroll
  for (int s = 0; s < 8; ++s) {
    bf16x8 ah = LDF(C0, arow, s, hb),  al = LDF(C1, arow, s, hb);
    bf16x8 b0h = LDF(C2, bcol0, s, hb), b0l = LDF(C3, bcol0, s, hb);
    bf16x8 b1h = LDF(C2, bcol1, s, hb), b1l = LDF(C3, bcol1, s, hb);
    p0 = MF(ah, b0h, p0); p0 = MF(ah, b0l, p0); p0 = MF(al, b0h, p0);
    p1 = MF(ah, b1h, p1); p1 = MF(ah, b1l, p1); p1 = MF(al, b1h, p1);
  }
  __syncthreads();

  // ---- U0 = cos - i sin: C0/C1 = Re hi/lo, C2/C3 = Im hi/lo ----
  STORE_TILE(Cc0, 1.0f, bcol0, C0, C1);
  STORE_TILE(Cc1, 1.0f, bcol1, C0, C1);
  STORE_TILE(p0, -1.0f, bcol0, C2, C3);
  STORE_TILE(p1, -1.0f, bcol1, C2, C3);
  __syncthreads();

  // ---- Squarings: Re' = R@R - I@I ; Im' = 2*(R@I) ----
  for (int sq = 0; sq < NSQ; ++sq) {
    f32x16 cr0, ci0, cr1, ci1;
#pragma unroll
    for (int e = 0; e < 16; ++e) { cr0[e] = 0; ci0[e] = 0; cr1[e] = 0; ci1[e] = 0; }
#pragma unroll
    for (int s = 0; s < 8; ++s) {
      bf16x8 aRh = LDF(C0, arow, s, hb), aRl = LDF(C1, arow, s, hb);
      bf16x8 aIh = LDF(C2, arow, s, hb), aIl = LDF(C3, arow, s, hb);
      bf16x8 aIhN = NEG(aIh), aIlN = NEG(aIl);
      bf16x8 bRh0 = LDF(C0, bcol0, s, hb), bRl0 = LDF(C1, bcol0, s, hb);
      bf16x8 bIh0 = LDF(C2, bcol0, s, hb), bIl0 = LDF(C3, bcol0, s, hb);
      bf16x8 bRh1 = LDF(C0, bcol1, s, hb), bRl1 = LDF(C1, bcol1, s, hb);
      bf16x8 bIh1 = LDF(C2, bcol1, s, hb), bIl1 = LDF(C3, bcol1, s, hb);
      cr0 = MF(aRh, bRh0, cr0); cr0 = MF(aRh, bRl0, cr0); cr0 = MF(aRl, bRh0, cr0);
      cr0 = MF(aIhN, bIh0, cr0); cr0 = MF(aIhN, bIl0, cr0); cr0 = MF(aIlN, bIh0, cr0);
      ci0 = MF(aRh, bIh0, ci0); ci0 = MF(aRh, bIl0, ci0); ci0 = MF(aRl, bIh0, ci0);
      cr1 = MF(aRh, bRh1, cr1); cr1 = MF(aRh, bRl1, cr1); cr1 = MF(aRl, bRh1, cr1);
      cr1 = MF(aIhN, bIh1, cr1); cr1 = MF(aIhN, bIl1, cr1); cr1 = MF(aIlN, bIh1, cr1);
      ci1 = MF(aRh, bIh1, ci1); ci1 = MF(aRh, bIl1, ci1); ci1 = MF(aRl, bIh1, ci1);
    }
    __syncthreads();
    if (sq < NSQ - 1) {
      STORE_TILE(cr0, 1.0f, bcol0, C0, C1);
      STORE_TILE(ci0, 2.0f, bcol0, C2, C3);
      STORE_TILE(cr1, 1.0f, bcol1, C0, C1);
      STORE_TILE(ci1, 2.0f, bcol1, C2, C3);
    } else {
#pragma unroll
      for (int q = 0; q < 4; ++q) {
        int off0 = bcol0 * FSTR + 32 * tr + 8 * q + 4 * hb;
        int off1 = bcol1 * FSTR + 32 * tr + 8 * q + 4 * hb;
        *(float4*)(Urf + off0) = make_float4(cr0[4*q], cr0[4*q+1], cr0[4*q+2], cr0[4*q+3]);
        *(float4*)(Uif + off0) = make_float4(2.0f*ci0[4*q], 2.0f*ci0[4*q+1], 2.0f*ci0[4*q+2], 2.0f*ci0[4*q+3]);
        *(float4*)(Urf + off1) = make_float4(cr1[4*q], cr1[4*q+1], cr1[4*q+2], cr1[4*q+3]);
        *(float4*)(Uif + off1) = make_float4(2.0f*ci1[4*q], 2.0f*ci1[4*q+1], 2.0f*ci1[4*q+2], 2.0f*ci1[4*q+3]);
      }
    }
    __syncthreads();
  }

  // ---- Butterfly G = F @ U on fp32 overlay ----
  const int* bq = basis + b * NQQ;
  const float sv = 0.70710678118654752f;
  for (int q = 0; q < NQQ; ++q) {
    int g = bq[q];
    if (g == 2) continue;
    const int bit = 6 - q;
    float g00r, g01r, g01i, g10r, g11r, g11i;
    if (g == 0) { g00r = sv; g01r = sv; g01i = 0;   g10r = sv; g11r = -sv; g11i = 0;  }
    else        { g00r = sv; g01r = 0;  g01i = -sv; g10r = sv; g11r = 0;   g11i = sv; }
    for (int jj = tid; jj < 64 * 32; jj += 512) {
      int cg = jj & 31;
      int p  = jj >> 5;
      int low = p & ((1 << bit) - 1);
      int i0 = ((p >> bit) << (bit + 1)) | low;
      int i1 = i0 | (1 << bit);
      float4 a0 = *(float4*)(Urf + i0 * FSTR + 4 * cg);
      float4 b0 = *(float4*)(Uif + i0 * FSTR + 4 * cg);
      float4 a1 = *(float4*)(Urf + i1 * FSTR + 4 * cg);
      float4 b1 = *(float4*)(Uif + i1 * FSTR + 4 * cg);
      float4 n0r, n0i, n1r, n1i;
#define BFLY(cc) { \
      float A0 = a0.cc, B0 = b0.cc, A1 = a1.cc, B1 = b1.cc; \
      n0r.cc = g00r * A0 + g01r * A1 - g01i * B1; \
      n0i.cc = g00r * B0 + g01r * B1 + g01i * A1; \
      n1r.cc = g10r * A0 + g11r * A1 - g11i * B1; \
      n1i.cc = g10r * B0 + g11r * B1 + g11i * A1; }
      BFLY(x) BFLY(y) BFLY(z) BFLY(w)
#undef BFLY
      *(float4*)(Urf + i0 * FSTR + 4 * cg) = n0r;
      *(float4*)(Uif + i0 * FSTR + 4 * cg) = n0i;
      *(float4*)(Urf + i1 * FSTR + 4 * cg) = n1r;
      *(float4*)(Uif + i1 * FSTR + 4 * cg) = n1i;
    }
    __syncthreads();
  }

  // ---- Re-layout fp32 G -> bf16 chunks ----
  {
    const int i  = tid >> 2;
    const int j0 = (tid & 3) * 32;
    float vr[32], vi[32];
#pragma unroll
    for (int c = 0; c < 8; ++c) {
      float4 x = *(float4*)(Urf + i * FSTR + j0 + 4 * c);
      vr[4*c+0] = x.x; vr[4*c+1] = x.y; vr[4*c+2] = x.z; vr[4*c+3] = x.w;
      float4 y = *(float4*)(Uif + i * FSTR + j0 + 4 * c);
      vi[4*c+0] = y.x; vi[4*c+1] = y.y; vi[4*c+2] = y.z; vi[4*c+3] = y.w;
    }
    __syncthreads();
#pragma unroll
    for (int blkc = 0; blkc < 4; ++blkc) {
      bf16x8 h, lo, h2, lo2;
#pragma unroll
      for (int e2 = 0; e2 < 8; ++e2) {
        unsigned short hh, ll;
        split2(vr[blkc * 8 + e2], hh, ll);  h[e2] = (short)hh;  lo[e2] = (short)ll;
        split2(vi[blkc * 8 + e2], hh, ll);  h2[e2] = (short)hh; lo2[e2] = (short)ll;
      }
      int off = i * CSTR + j0 + blkc * 8;
      *(bf16x8*)(C0 + off) = h;  *(bf16x8*)(C1 + off) = lo;
      *(bf16x8*)(C2 + off) = h2; *(bf16x8*)(C3 + off) = lo2;
    }
    __syncthreads();
  }

  // ---- Phase 4: W = rho @ conj(G)^T; d_i = sum_k G_ik W_ki ----
  // wave -> (slab, part). Col-tiles processed in 2 SERIAL passes of 2
  // accumulators (32 VGPR live) instead of 4 (64) -> fits 128-VGPR budget
  // without scratch spill (R5/R6: 313MB/dispatch spill writes).
  const int slab = wid >> 1;
  const int part = wid & 1;
  const float* srow = state + (size_t)b * (DD * DD * 2) + (size_t)(32 * slab + l31) * 256;

#pragma unroll 1
  for (int ch = 0; ch < 2; ++ch) {
    const int n40 = 2 * ch;
    const int n41 = 2 * ch + 1;
    f32x16 w0, w1;
#pragma unroll
    for (int e = 0; e < 16; ++e) { w0[e] = 0; w1[e] = 0; }

    for (int s = 0; s < 8; ++s) {
      const float* pp = srow + (s * 16 + hb * 8) * 2;
      float4 q0 = *(const float4*)(pp);
      float4 q1 = *(const float4*)(pp + 4);
      float4 q2 = *(const float4*)(pp + 8);
      float4 q3 = *(const float4*)(pp + 12);
      float re[8] = {q0.x, q0.z, q1.x, q1.z, q2.x, q2.z, q3.x, q3.z};
      float im[8] = {q0.y, q0.w, q1.y, q1.w, q2.y, q2.w, q3.y, q3.w};
      bf16x8 rh, rl, ihh, ill;
#pragma unroll
      for (int e2 = 0; e2 < 8; ++e2) {
        unsigned short hh, ll;
        split2(re[e2], hh, ll); rh[e2] = (short)hh;  rl[e2] = (short)ll;
        split2(im[e2], hh, ll); ihh[e2] = (short)hh; ill[e2] = (short)ll;
      }
      bf16x8 rhn = NEG(rh), rln = NEG(rl);
#define P4N4(WREG, N4) do {                                                \
    int gcol_ = 32 * (N4) + l31;                                           \
    bf16x8 gRh = LDF(C0, gcol_, s, hb), gRl = LDF(C1, gcol_, s, hb);       \
    bf16x8 gIh = LDF(C2, gcol_, s, hb), gIl = LDF(C3, gcol_, s, hb);       \
    if (part == 0) {                                                       \
      WREG = MF(rh, gRh, WREG);  WREG = MF(rh, gRl, WREG);  WREG = MF(rl, gRh, WREG); \
      WREG = MF(ihh, gIh, WREG); WREG = MF(ihh, gIl, WREG); WREG = MF(ill, gIh, WREG); \
    } else {                                                               \
      WREG = MF(ihh, gRh, WREG); WREG = MF(ihh, gRl, WREG); WREG = MF(ill, gRh, WREG); \
      WREG = MF(rhn, gIh, WREG); WREG = MF(rhn, gIl, WREG); WREG = MF(rln, gIh, WREG); \
    }                                                                      \
  } while (0)
      P4N4(w0, n40); P4N4(w1, n41);
#undef P4N4
    }

    // dot: partial_{which}[i] over this slab's k-range
#define P4DOT(WREG, N4) do {                                               \
    int gcol_ = 32 * (N4) + l31;                                           \
    float a1 = 0.0f, a2 = 0.0f;                                            \
    _Pragma("unroll")                                                      \
    for (int q_ = 0; q_ < 4; ++q_) {                                       \
      int koff = 32 * slab + 8 * q_ + 4 * hb;                              \
      s16x4 grh = *(const s16x4*)(C0 + gcol_ * CSTR + koff);               \
      s16x4 grl = *(const s16x4*)(C1 + gcol_ * CSTR + koff);               \
      s16x4 gih = *(const s16x4*)(C2 + gcol_ * CSTR + koff);               \
      s16x4 gil = *(const s16x4*)(C3 + gcol_ * CSTR + koff);               \
      _Pragma("unroll")                                                    \
      for (int rr_ = 0; rr_ < 4; ++rr_) {                                  \
        float wv = WREG[4 * q_ + rr_];                                     \
        float gr = bf2f((unsigned short)grh[rr_]) + bf2f((unsigned short)grl[rr_]); \
        float gi = bf2f((unsigned short)gih[rr_]) + bf2f((unsigned short)gil[rr_]); \
        a1 = fmaf(gr, wv, a1); a2 = fmaf(gi, wv, a2);                      \
      }                                                                    \
    }                                                                      \
    a1 += __shfl_xor(a1, 32); a2 += __shfl_xor(a2, 32);                    \
    if (lane < 32) {                                                       \
      AUX[((part * 2 + 0) * 4 + slab) * 128 + 32 * (N4) + l31] = a1;       \
      AUX[((part * 2 + 1) * 4 + slab) * 128 + 32 * (N4) + l31] = a2;       \
    }                                                                      \
  } while (0)
    P4DOT(w0, n40); P4DOT(w1, n41);
#undef P4DOT
  }
  __syncthreads();

  if (tid < 128) {
    float s0 = 0, s1 = 0, s2 = 0, s3 = 0;
#pragma unroll
    for (int sl = 0; sl < 4; ++sl) {
      s0 += AUX[(0 * 4 + sl) * 128 + tid];   // Gr.Wr
      s1 += AUX[(1 * 4 + sl) * 128 + tid];   // Gi.Wr
      s2 += AUX[(2 * 4 + sl) * 128 + tid];   // Gr.Wi
      s3 += AUX[(3 * 4 + sl) * 128 + tid];   // Gi.Wi
    }
    float dr = s0 - s3, di = s2 + s1;
    AUX[tid] = dr * dr + di * di;
  }
  __syncthreads();
  if (tid < 64) {
    float ps = AUX[tid] + AUX[tid + 64];
#pragma unroll
    for (int o = 32; o >= 1; o >>= 1) ps += __shfl_xor(ps, o);
    if (tid == 0) {
      float pt = AUX[tgt[b]];
      float tp = fmaxf(pt / ps, 1e-12f);
      ws[b] = -logf(tp) * (1.0f / (float)NQQ);
    }
  }
#undef STORE_TILE
}

// Deterministic 1024 -> 1 mean.
__global__ __launch_bounds__(256) void reduce_k(const float* __restrict__ ws,
                                                float* __restrict__ out)
{
  __shared__ float s[256];
  const int tid = threadIdx.x;
  float v = ws[tid] + ws[tid + 256] + ws[tid + 512] + ws[tid + 768];
  s[tid] = v;
  __syncthreads();
  for (int o = 128; o > 0; o >>= 1) {
    if (tid < o) s[tid] += s[tid + o];
    __syncthreads();
  }
  if (tid == 0) out[0] = s[0] * (1.0f / (float)NB);
}

extern "C" void kernel_launch(void* const* d_in, const int* in_sizes, int n_in,
                              void* d_out, int out_size, void* d_ws, size_t ws_size,
                              hipStream_t stream) {
  const float* flat  = (const float*)d_in[0];
  const float* tv    = (const float*)d_in[1];
  const float* st    = (const float*)d_in[2];
  const int*   tgt   = (const int*)d_in[3];
  const int*   basis = (const int*)d_in[4];
  float* out = (float*)d_out;
  float* ws  = (float*)d_ws;

  hipLaunchKernelGGL(loss_k, dim3(NB), dim3(512), 0, stream,
                     flat, tv, st, tgt, basis, ws);
  hipLaunchKernelGGL(reduce_k, dim3(1), dim3(256), 0, stream, ws, out);
}